// Round 17
// baseline (173.710 us; speedup 1.0000x reference)
//
#include <hip/hip_runtime.h>

constexpr int D_IN = 20;   // input feature dim
constexpr int HP   = 16;   // projection dim
constexpr int K    = 6;    // neighbors
constexpr int SAMP = 512;  // threshold sample size
constexpr int NC   = 8;    // candidate chunks (segmented buffers)
constexpr int CAPC = 192;  // per-(row,chunk) buffer capacity
constexpr int CIN  = 128;  // per-row in-edge slots
constexpr float MARGIN = 0.02f;  // covers bf16-vs-fp32 dot error

typedef __attribute__((ext_vector_type(8))) short bf16x8;
typedef __attribute__((ext_vector_type(4))) float f32x4;

// Sequential fmaf dot — MUST be bit-identical across thresh/final.
__device__ __forceinline__ float dot16_seq(const float4* q, const float4* c) {
  float s = 0.f;
#pragma unroll
  for (int m = 0; m < 4; ++m) {
    s = fmaf(q[m].x, c[m].x, s);
    s = fmaf(q[m].y, c[m].y, s);
    s = fmaf(q[m].z, c[m].z, s);
    s = fmaf(q[m].w, c[m].w, s);
  }
  return s;
}

// round-to-nearest-even f32 -> bf16 bits
__device__ __forceinline__ short f2bf(float f) {
  unsigned u = __float_as_uint(f);
  unsigned r = (u + 0x7fffu + ((u >> 16) & 1u)) >> 16;
  return (short)r;
}

__device__ __forceinline__ float dinv_of(float own, float ins) {
  float rs = 0.5f * (own + ins);
  float rn = 1.f / (rs + 1e-8f);
  return rsqrtf(fmaxf(1.f + rs * rn, 1e-12f));
}

// ---- projection + row-normalize + bf16 copy + XW0 + counter zeroing ----
__global__ void k_proj(const float* __restrict__ x, const float* __restrict__ Wp,
                       const float* __restrict__ bp, const float* __restrict__ gw0,
                       float* __restrict__ hn, short* __restrict__ hnb,
                       float* __restrict__ XW0,
                       float* __restrict__ insum, int* __restrict__ indeg, int N) {
  int i = blockIdx.x * blockDim.x + threadIdx.x;
  if (i >= N) return;
  insum[i] = 0.f; indeg[i] = 0;
  float xr[D_IN];
#pragma unroll
  for (int d = 0; d < D_IN; ++d) xr[d] = x[i*D_IN + d];
  float hv[HP];
  float nrm2 = 0.f;
#pragma unroll
  for (int h = 0; h < HP; ++h) {
    float a = bp[h];
#pragma unroll
    for (int d = 0; d < D_IN; ++d) a += xr[d] * Wp[d*HP + h];
    hv[h] = a;
    nrm2 += a * a;
  }
  float inv = 1.f / fmaxf(sqrtf(nrm2), 1e-12f);
#pragma unroll
  for (int h = 0; h < HP; ++h) {
    float v = hv[h] * inv;
    hn[i*HP + h] = v;
    hnb[(size_t)i*32 + h] = f2bf(v);
  }
#pragma unroll
  for (int h = 0; h < HP; ++h) hnb[(size_t)i*32 + 16 + h] = 0;
#pragma unroll
  for (int oc = 0; oc < 32; ++oc) {
    float a = 0.f;
#pragma unroll
    for (int d = 0; d < D_IN; ++d) a += xr[d] * gw0[d*32 + oc];
    XW0[(size_t)i*32 + oc] = a;
  }
}

// ---------------- per-lane top-6 in NAMED registers ----
struct Top6 { float v0,v1,v2,v3,v4,v5; int i0,i1,i2,i3,i4,i5; };

__device__ __forceinline__ void t6_init(Top6& t) {
  t.v0=t.v1=t.v2=t.v3=t.v4=t.v5=-1e30f;
  t.i0=t.i1=t.i2=t.i3=t.i4=t.i5=-1;
}

#define T6_SWAP(a,b,ia,ib) { float tv=a; a=b; b=tv; int ti=ia; ia=ib; ib=ti; }

__device__ __forceinline__ void t6_insert(Top6& t, float s, int c) {
  if (s > t.v5) {
    t.v5 = s; t.i5 = c;
    if (t.v5 > t.v4) { T6_SWAP(t.v4, t.v5, t.i4, t.i5); }
    if (t.v4 > t.v3) { T6_SWAP(t.v3, t.v4, t.i3, t.i4); }
    if (t.v3 > t.v2) { T6_SWAP(t.v2, t.v3, t.i2, t.i3); }
    if (t.v2 > t.v1) { T6_SWAP(t.v1, t.v2, t.i1, t.i2); }
    if (t.v1 > t.v0) { T6_SWAP(t.v0, t.v1, t.i0, t.i1); }
  }
}

__device__ __forceinline__ void t6_best(const Top6& t, float& cv, int& ci) {
  cv = t.v0; ci = t.i0;
  if (t.v1 > cv || (t.v1 == cv && (unsigned)t.i1 < (unsigned)ci)) { cv = t.v1; ci = t.i1; }
  if (t.v2 > cv || (t.v2 == cv && (unsigned)t.i2 < (unsigned)ci)) { cv = t.v2; ci = t.i2; }
  if (t.v3 > cv || (t.v3 == cv && (unsigned)t.i3 < (unsigned)ci)) { cv = t.v3; ci = t.i3; }
  if (t.v4 > cv || (t.v4 == cv && (unsigned)t.i4 < (unsigned)ci)) { cv = t.v4; ci = t.i4; }
  if (t.v5 > cv || (t.v5 == cv && (unsigned)t.i5 < (unsigned)ci)) { cv = t.v5; ci = t.i5; }
}

__device__ __forceinline__ void t6_consume(Top6& t, int mi) {
  if (t.i0 == mi) t.v0 = -1e30f;
  if (t.i1 == mi) t.v1 = -1e30f;
  if (t.i2 == mi) t.v2 = -1e30f;
  if (t.i3 == mi) t.v3 = -1e30f;
  if (t.i4 == mi) t.v4 = -1e30f;
  if (t.i5 == mi) t.v5 = -1e30f;
}

// ---------------- threshold pass: exact 6th-largest over SAMP-sample, wave per row
__global__ __launch_bounds__(256) void k_thresh(const float* __restrict__ hn,
                                                float* __restrict__ tau, int N) {
  int wave = threadIdx.x >> 6, lane = threadIdx.x & 63;
  int row = blockIdx.x * 4 + wave;
  const float4* hn4 = (const float4*)hn;
  float4 q[4];
#pragma unroll
  for (int m = 0; m < 4; ++m) q[m] = hn4[(size_t)row*4 + m];
  Top6 t; t6_init(t);
#pragma unroll
  for (int k = 0; k < SAMP/64; ++k) {
    int c = lane + 64*k;
    if (c != row) {
      float4 cv[4];
#pragma unroll
      for (int m = 0; m < 4; ++m) cv[m] = hn4[(size_t)c*4 + m];
      float s = dot16_seq(q, cv);
      t6_insert(t, s, c);
    }
  }
  float last = -1e30f;
  for (int sel = 0; sel < K; ++sel) {
    float cv; int ci;
    t6_best(t, cv, ci);
    float mv = cv; int mi = ci;
#pragma unroll
    for (int m = 1; m < 64; m <<= 1) {
      float ov = __shfl_xor(mv, m);
      int   oi = __shfl_xor(mi, m);
      if (ov > mv || (ov == mv && (unsigned)oi < (unsigned)mi)) { mv = ov; mi = oi; }
    }
    t6_consume(t, mi);
    last = mv;
  }
  if (lane == 0) tau[row] = last;
}

// ---------------- MFMA threshold scan: segmented XCD-local appends ----------------
__global__ __launch_bounds__(256) void k_scan2(
    const short* __restrict__ hnb, const float* __restrict__ tau,
    int* __restrict__ cnt, unsigned short* __restrict__ buf, int N) {
  __shared__ int cntl[16];
  int rb = blockIdx.x / NC;          // row group
  int jc = blockIdx.x % NC;          // candidate chunk
  int wave = threadIdx.x >> 6, lane = threadIdx.x & 63;
  int r0 = rb * 16;
  int half = lane >> 4;              // 0..3
  int l16  = lane & 15;

  if (threadIdx.x < 16) cntl[threadIdx.x] = 0;
  __syncthreads();

  bf16x8 a = *(const bf16x8*)(hnb + (size_t)(r0 + l16)*32 + half*8);
  float4 t4 = *(const float4*)(tau + r0 + half*4);
  float tm0 = t4.x - MARGIN, tm1 = t4.y - MARGIN,
        tm2 = t4.z - MARGIN, tm3 = t4.w - MARGIN;
  f32x4 zero = {0.f, 0.f, 0.f, 0.f};

  const int SPANW = N / NC / 4;      // cands per wave (256)
  int jb0 = jc * (N / NC) + wave * SPANW;

#define APPB(R, COND)                                                        \
  {                                                                          \
    unsigned long long mr = __ballot(COND);                                  \
    if (l16 == 0) {                                                          \
      unsigned mask = (unsigned)(mr >> (16*half)) & 0xFFFFu;                 \
      if (mask) {                                                            \
        int row = r0 + half*4 + (R);                                         \
        int pos = atomicAdd(&cntl[4*half + (R)], __popc(mask));              \
        unsigned mm = mask;                                                  \
        while (mm) {                                                         \
          int bx = __ffs(mm) - 1; mm &= mm - 1;                              \
          if (pos < CAPC)                                                    \
            buf[((size_t)row*NC + jc)*CAPC + pos] = (unsigned short)(jb + bx); \
          ++pos;                                                             \
        }                                                                    \
      }                                                                      \
    }                                                                        \
  }

#pragma unroll 4
  for (int jt = 0; jt < SPANW; jt += 16) {
    int jb = jb0 + jt;
    bf16x8 b = *(const bf16x8*)(hnb + (size_t)(jb + l16)*32 + half*8);
    f32x4 d = __builtin_amdgcn_mfma_f32_16x16x32_bf16(a, b, zero, 0, 0, 0);
    bool h0 = d[0] >= tm0, h1 = d[1] >= tm1, h2 = d[2] >= tm2, h3 = d[3] >= tm3;
    if (__any(h0 | h1 | h2 | h3)) {
      APPB(0, h0) APPB(1, h1) APPB(2, h2) APPB(3, h3)
    }
  }
#undef APPB

  __syncthreads();
  if (threadIdx.x < 16)
    cnt[(size_t)(r0 + threadIdx.x)*NC + jc] = min(cntl[threadIdx.x], CAPC);
}

// ---- exact top-6 (flattened segments) + direct in-edge slot writes, wave per row --
__global__ __launch_bounds__(256) void k_final(
    const float* __restrict__ hn, const unsigned short* __restrict__ buf,
    const int* __restrict__ cnt,
    float* __restrict__ evals, int* __restrict__ eidx,
    float* __restrict__ ownsum, float* insum, int* indeg,
    unsigned short* __restrict__ incol, float* __restrict__ inval, int N) {
  int wave = threadIdx.x >> 6, lane = threadIdx.x & 63;
  int row = blockIdx.x * 4 + wave;
  const float4* hn4 = (const float4*)hn;
  float4 q[4];
#pragma unroll
  for (int m = 0; m < 4; ++m) q[m] = hn4[(size_t)row*4 + m];

  int cbase = row * NC;
  int cl = (lane < NC) ? cnt[cbase + lane] : 0;
  int c0 = __shfl(cl, 0), c1 = __shfl(cl, 1), c2 = __shfl(cl, 2), c3 = __shfl(cl, 3),
      c4 = __shfl(cl, 4), c5 = __shfl(cl, 5), c6 = __shfl(cl, 6), c7 = __shfl(cl, 7);
  int p1 = c0, p2 = p1 + c1, p3 = p2 + c2, p4 = p3 + c3,
      p5 = p4 + c4, p6 = p5 + c5, p7 = p6 + c6, T = p7 + c7;

  Top6 t; t6_init(t);
  for (int e = lane; e < T; e += 64) {
    int s, off;
    if (e < p4) {
      if (e < p2) { if (e < p1) { s = 0; off = e; } else { s = 1; off = e - p1; } }
      else        { if (e < p3) { s = 2; off = e - p2; } else { s = 3; off = e - p3; } }
    } else {
      if (e < p6) { if (e < p5) { s = 4; off = e - p4; } else { s = 5; off = e - p5; } }
      else        { if (e < p7) { s = 6; off = e - p6; } else { s = 7; off = e - p7; } }
    }
    int j = buf[((size_t)cbase + s)*CAPC + off];
    if (j != row) {
      float4 cv[4];
#pragma unroll
      for (int m = 0; m < 4; ++m) cv[m] = hn4[(size_t)j*4 + m];
      float sc = dot16_seq(q, cv);
      t6_insert(t, sc, j);
    }
  }
  float osum = 0.f;
  for (int sel = 0; sel < K; ++sel) {
    float cv; int ci;
    t6_best(t, cv, ci);
    float mv = cv; int mi = ci;
#pragma unroll
    for (int m = 1; m < 64; m <<= 1) {
      float ov = __shfl_xor(mv, m);
      int   oi = __shfl_xor(mi, m);
      if (ov > mv || (ov == mv && (unsigned)oi < (unsigned)mi)) { mv = ov; mi = oi; }
    }
    t6_consume(t, mi);
    if (lane == 0) {
      evals[row*K + sel] = mv;
      eidx [row*K + sel] = mi;
      osum += mv;
      atomicAdd(&insum[mi], mv);
      int pos = atomicAdd(&indeg[mi], 1);
      if (pos < CIN) {
        incol[(size_t)mi*CIN + pos] = (unsigned short)row;
        inval[(size_t)mi*CIN + pos] = mv;
      }
    }
  }
  if (lane == 0) ownsum[row] = osum;
}

// ---- DOUT=32 layer: GCN + LN + ReLU + MLP residual, 2 rows/wave.
// FIRST=true: compute coefficients from ownsum/insum/evals and CACHE them
// (selfc, coefK, coefIN) for the later layers. FIRST=false: load cached coefs.
// Epilogue computes next layer's XW row-locally (h shared via LDS).
template<int DIN, int NEXTD, bool FIRST>
__global__ __launch_bounds__(256) void k_gpost32(
    const float* __restrict__ XWsrc,
    const int* __restrict__ eidx, const float* __restrict__ evals,
    const unsigned short* __restrict__ incol, const float* __restrict__ inval,
    const int* __restrict__ indeg,
    const float* __restrict__ ownsum, const float* __restrict__ insum,
    float* __restrict__ selfc, float* __restrict__ coefK, float* __restrict__ coefIN,
    const float* __restrict__ gb, const float* __restrict__ lg, const float* __restrict__ lb,
    const float* __restrict__ hprev,
    const float* __restrict__ w0, const float* __restrict__ b0,
    const float* __restrict__ w1, const float* __restrict__ b1,
    const float* __restrict__ Wnext, float* __restrict__ XWnext,
    float* __restrict__ outp, int N) {
  __shared__ float hid[4][2][32];
  int tid = threadIdx.x;
  int lane = tid & 63, wslot = tid >> 6;
  int sub = lane >> 5, ol = lane & 31;
  int row = (blockIdx.x * 4 + wslot) * 2 + sub;

  float acc;
  int ne = min(indeg[row], CIN);
  if constexpr (FIRST) {
    float rs_i = 0.5f * (ownsum[row] + insum[row]);
    float rn_i = 1.f / (rs_i + 1e-8f);
    float di_i = rsqrtf(fmaxf(1.f + rs_i * rn_i, 1e-12f));
    float cc = 0.5f * di_i * rn_i;
    float sc = di_i * di_i;
    if (ol == 0) selfc[row] = sc;
    acc = sc * XWsrc[(size_t)row*32 + ol];
#pragma unroll
    for (int t = 0; t < K; ++t) {
      int j = eidx[row*K + t]; float v = evals[row*K + t];
      float dj = dinv_of(ownsum[j], insum[j]);
      float cf = cc * v * dj;
      if (ol == 0) coefK[row*K + t] = cf;
      acc = fmaf(cf, XWsrc[(size_t)j*32 + ol], acc);
    }
    for (int e = 0; e < ne; ++e) {
      int j = incol[(size_t)row*CIN + e]; float v = inval[(size_t)row*CIN + e];
      float dj = dinv_of(ownsum[j], insum[j]);
      float cf = cc * v * dj;
      if (ol == 0) coefIN[(size_t)row*CIN + e] = cf;
      acc = fmaf(cf, XWsrc[(size_t)j*32 + ol], acc);
    }
  } else {
    acc = selfc[row] * XWsrc[(size_t)row*32 + ol];
#pragma unroll
    for (int t = 0; t < K; ++t) {
      int j = eidx[row*K + t]; float cf = coefK[row*K + t];
      acc = fmaf(cf, XWsrc[(size_t)j*32 + ol], acc);
    }
    const unsigned short* icp = incol + (size_t)row*CIN;
    const float* cfp = coefIN + (size_t)row*CIN;
    for (int e0 = 0; e0 < ne; e0 += 4) {
      int j0 = icp[e0];                          float cf0 = cfp[e0];
      int b1v = e0+1 < ne, b2v = e0+2 < ne, b3v = e0+3 < ne;
      int j1 = b1v ? icp[e0+1] : j0;             float cf1 = b1v ? cfp[e0+1] : 0.f;
      int j2 = b2v ? icp[e0+2] : j0;             float cf2 = b2v ? cfp[e0+2] : 0.f;
      int j3 = b3v ? icp[e0+3] : j0;             float cf3 = b3v ? cfp[e0+3] : 0.f;
      float v0 = XWsrc[(size_t)j0*32 + ol], v1 = XWsrc[(size_t)j1*32 + ol],
            v2 = XWsrc[(size_t)j2*32 + ol], v3 = XWsrc[(size_t)j3*32 + ol];
      acc = fmaf(cf0, v0, acc);
      acc = fmaf(cf1, v1, acc);
      acc = fmaf(cf2, v2, acc);
      acc = fmaf(cf3, v3, acc);
    }
  }
  float u0 = acc + gb[ol];
  float s = u0;
#pragma unroll
  for (int m = 1; m < 32; m <<= 1) s += __shfl_xor(s, m);
  float mean = s * (1.f/32.f);
  float d0 = u0 - mean;
  float vs = d0*d0;
#pragma unroll
  for (int m = 1; m < 32; m <<= 1) vs += __shfl_xor(vs, m);
  float rstd = rsqrtf(vs * (1.f/32.f) + 1e-5f);
  float t0 = fmaxf(d0*rstd*lg[ol] + lb[ol], 0.f);

  // MLP residual (per-wave LDS; same-wave lockstep -> no barrier)
  float hp[DIN];
#pragma unroll
  for (int d = 0; d < DIN; ++d) hp[d] = hprev[(size_t)row*DIN + d];
  float a = b0[ol];
#pragma unroll
  for (int d = 0; d < DIN; ++d) a = fmaf(hp[d], w0[d*32 + ol], a);
  hid[wslot][sub][ol] = fmaxf(a, 0.f);
  // w1 product with ILP-4 partials (chain 32 -> 8)
  float r0 = 0.f, r1 = 0.f, r2 = 0.f, r3 = 0.f;
#pragma unroll
  for (int h = 0; h < 32; h += 4) {
    r0 = fmaf(hid[wslot][sub][h+0], w1[(h+0)*32 + ol], r0);
    r1 = fmaf(hid[wslot][sub][h+1], w1[(h+1)*32 + ol], r1);
    r2 = fmaf(hid[wslot][sub][h+2], w1[(h+2)*32 + ol], r2);
    r3 = fmaf(hid[wslot][sub][h+3], w1[(h+3)*32 + ol], r3);
  }
  float hv = t0 + b1[ol] + ((r0 + r1) + (r2 + r3));
  outp[(size_t)row*32 + ol] = hv;

  // epilogue: XWnext = h @ Wnext (h row shared via LDS), ILP-4
  hid[wslot][sub][ol] = hv;
#pragma unroll
  for (int k2 = 0; k2 < NEXTD/32; ++k2) {
    int oc = ol + 32*k2;
    float e0 = 0.f, e1 = 0.f, e2 = 0.f, e3 = 0.f;
#pragma unroll
    for (int d = 0; d < 32; d += 4) {
      e0 = fmaf(hid[wslot][sub][d+0], Wnext[(d+0)*NEXTD + oc], e0);
      e1 = fmaf(hid[wslot][sub][d+1], Wnext[(d+1)*NEXTD + oc], e1);
      e2 = fmaf(hid[wslot][sub][d+2], Wnext[(d+2)*NEXTD + oc], e2);
      e3 = fmaf(hid[wslot][sub][d+3], Wnext[(d+3)*NEXTD + oc], e3);
    }
    XWnext[(size_t)row*NEXTD + oc] = (e0 + e1) + (e2 + e3);
  }
}

// ---------------- final layer (DOUT=128): paired-column float2 layout ----
// lane owns cols (2*lane, 2*lane+1): every XW/w0/w1/out access is one float2.
__global__ __launch_bounds__(256) void k_gpost128(
    const float* __restrict__ XW,
    const int* __restrict__ eidx, const float* __restrict__ coefK,
    const unsigned short* __restrict__ incol, const float* __restrict__ coefIN,
    const int* __restrict__ indeg, const float* __restrict__ selfc,
    const float* __restrict__ b, const float* __restrict__ g, const float* __restrict__ bt,
    const float* __restrict__ hprev,
    const float* __restrict__ w0, const float* __restrict__ b0,
    const float* __restrict__ w1, const float* __restrict__ b1,
    float* __restrict__ out, int N) {
  __shared__ float hid_s[4][128];
  int wslot = threadIdx.x >> 6;
  int row   = (blockIdx.x * blockDim.x + threadIdx.x) >> 6;
  int lane  = threadIdx.x & 63;
  const float2* XW2 = (const float2*)XW;   // row stride 64 float2

  float sc = selfc[row];
  float2 xs = XW2[(size_t)row*64 + lane];
  float acc0 = sc * xs.x, acc1 = sc * xs.y;
#pragma unroll
  for (int t = 0; t < K; ++t) {
    int j = eidx[row*K + t]; float cf = coefK[row*K + t];
    float2 v = XW2[(size_t)j*64 + lane];
    acc0 = fmaf(cf, v.x, acc0); acc1 = fmaf(cf, v.y, acc1);
  }
  int ne = min(indeg[row], CIN);
  const unsigned short* icp = incol + (size_t)row*CIN;
  const float* cfp = coefIN + (size_t)row*CIN;
  for (int e0 = 0; e0 < ne; e0 += 4) {
    int j0 = icp[e0];                      float c0 = cfp[e0];
    int b1v = e0+1 < ne, b2v = e0+2 < ne, b3v = e0+3 < ne;
    int j1 = b1v ? icp[e0+1] : j0;         float c1 = b1v ? cfp[e0+1] : 0.f;
    int j2 = b2v ? icp[e0+2] : j0;         float c2 = b2v ? cfp[e0+2] : 0.f;
    int j3 = b3v ? icp[e0+3] : j0;         float c3 = b3v ? cfp[e0+3] : 0.f;
    float2 v0 = XW2[(size_t)j0*64 + lane], v1 = XW2[(size_t)j1*64 + lane],
           v2 = XW2[(size_t)j2*64 + lane], v3 = XW2[(size_t)j3*64 + lane];
    acc0 = fmaf(c0, v0.x, acc0); acc1 = fmaf(c0, v0.y, acc1);
    acc0 = fmaf(c1, v1.x, acc0); acc1 = fmaf(c1, v1.y, acc1);
    acc0 = fmaf(c2, v2.x, acc0); acc1 = fmaf(c2, v2.y, acc1);
    acc0 = fmaf(c3, v3.x, acc0); acc1 = fmaf(c3, v3.y, acc1);
  }
  float2 bv = ((const float2*)b)[lane];
  float u0 = acc0 + bv.x, u1 = acc1 + bv.y;

  float s = u0 + u1;
#pragma unroll
  for (int m = 1; m < 64; m <<= 1) s += __shfl_xor(s, m);
  float mean = s * (1.f/128.f);
  float d0 = u0 - mean, d1 = u1 - mean;
  float vs = d0*d0 + d1*d1;
#pragma unroll
  for (int m = 1; m < 64; m <<= 1) vs += __shfl_xor(vs, m);
  float rstd = rsqrtf(vs * (1.f/128.f) + 1e-5f);
  float2 gv = ((const float2*)g)[lane], btv = ((const float2*)bt)[lane];
  float t0 = fmaxf(d0*rstd*gv.x + btv.x, 0.f);
  float t1 = fmaxf(d1*rstd*gv.y + btv.y, 0.f);

  float hp[32];
#pragma unroll
  for (int d = 0; d < 32; ++d) hp[d] = hprev[(size_t)row*32 + d];
  const float2* w02 = (const float2*)w0;   // row stride 64 float2
  float2 b0v = ((const float2*)b0)[lane];
  float a0 = b0v.x, a1 = b0v.y;
#pragma unroll
  for (int d = 0; d < 32; ++d) {
    float2 wv = w02[(size_t)d*64 + lane];
    a0 = fmaf(hp[d], wv.x, a0);
    a1 = fmaf(hp[d], wv.y, a1);
  }
  ((float2*)hid_s[wslot])[lane] = make_float2(fmaxf(a0, 0.f), fmaxf(a1, 0.f));
  __syncthreads();

  // out = hid @ w1: float2 loads + ILP-4 partials (chain 128 -> 32)
  const float2* w12 = (const float2*)w1;
  float r0=0.f, r1=0.f, r2=0.f, r3=0.f, q0=0.f, q1=0.f, q2=0.f, q3=0.f;
#pragma unroll
  for (int h = 0; h < 128; h += 4) {
    float h0 = hid_s[wslot][h+0], h1 = hid_s[wslot][h+1],
          h2 = hid_s[wslot][h+2], h3 = hid_s[wslot][h+3];
    float2 wa = w12[(size_t)(h+0)*64 + lane];
    float2 wb = w12[(size_t)(h+1)*64 + lane];
    float2 wc = w12[(size_t)(h+2)*64 + lane];
    float2 wd = w12[(size_t)(h+3)*64 + lane];
    r0 = fmaf(h0, wa.x, r0); q0 = fmaf(h0, wa.y, q0);
    r1 = fmaf(h1, wb.x, r1); q1 = fmaf(h1, wb.y, q1);
    r2 = fmaf(h2, wc.x, r2); q2 = fmaf(h2, wc.y, q2);
    r3 = fmaf(h3, wd.x, r3); q3 = fmaf(h3, wd.y, q3);
  }
  float2 b1v = ((const float2*)b1)[lane];
  float ox = t0 + b1v.x + ((r0 + r1) + (r2 + r3));
  float oy = t1 + b1v.y + ((q0 + q1) + (q2 + q3));
  ((float2*)out)[(size_t)row*64 + lane] = make_float2(ox, oy);
}

extern "C" void kernel_launch(void* const* d_in, const int* in_sizes, int n_in,
                              void* d_out, int out_size, void* d_ws, size_t ws_size,
                              hipStream_t stream) {
  const float* x    = (const float*)d_in[0];
  const float* Wp   = (const float*)d_in[1];
  const float* bp   = (const float*)d_in[2];
  const float* gw0  = (const float*)d_in[3];
  const float* gb0  = (const float*)d_in[4];
  const float* gw1  = (const float*)d_in[5];
  const float* gb1  = (const float*)d_in[6];
  const float* gw2  = (const float*)d_in[7];
  const float* gb2  = (const float*)d_in[8];
  const float* lg0  = (const float*)d_in[9];
  const float* lb0  = (const float*)d_in[10];
  const float* lg1  = (const float*)d_in[11];
  const float* lb1  = (const float*)d_in[12];
  const float* lg2  = (const float*)d_in[13];
  const float* lb2  = (const float*)d_in[14];
  const float* riw0 = (const float*)d_in[15];
  const float* rib0 = (const float*)d_in[16];
  const float* riw1 = (const float*)d_in[17];
  const float* rib1 = (const float*)d_in[18];
  const float* rhw0 = (const float*)d_in[19];
  const float* rhb0 = (const float*)d_in[20];
  const float* rhw1 = (const float*)d_in[21];
  const float* rhb1 = (const float*)d_in[22];
  const float* row0 = (const float*)d_in[23];
  const float* rob0 = (const float*)d_in[24];
  const float* row1 = (const float*)d_in[25];
  const float* rob1 = (const float*)d_in[26];
  int N = in_sizes[0] / D_IN;   // 8192
  float* out = (float*)d_out;

  char* ws = (char*)d_ws;
  size_t off = 0;
  auto alloc = [&](size_t bytes) -> void* {
    void* p = ws + off;
    off += (bytes + 255) & ~(size_t)255;
    return p;
  };
  float* hn      = (float*)alloc((size_t)N * HP * 4);
  float* evals   = (float*)alloc((size_t)N * K * 4);
  int*   eidx    = (int*)  alloc((size_t)N * K * 4);
  float* ownsum  = (float*)alloc((size_t)N * 4);
  float* insum   = (float*)alloc((size_t)N * 4);
  int*   indeg   = (int*)  alloc((size_t)N * 4);
  float* XWa     = (float*)alloc((size_t)N * 128 * 4);
  float* XWb     = (float*)alloc((size_t)N * 32 * 4);
  float* h1      = (float*)alloc((size_t)N * 32 * 4);
  float* h2      = (float*)alloc((size_t)N * 32 * 4);
  float* tau     = (float*)alloc((size_t)N * 4);
  int*   cnt     = (int*)  alloc((size_t)N * NC * 4);
  unsigned short* buf = (unsigned short*)alloc((size_t)N * NC * CAPC * 2);
  short* hnb     = (short*)alloc((size_t)N * 32 * 2);
  unsigned short* incol = (unsigned short*)alloc((size_t)N * CIN * 2);
  float* inval   = (float*)alloc((size_t)N * CIN * 4);
  float* selfc   = (float*)alloc((size_t)N * 4);
  float* coefK   = (float*)alloc((size_t)N * K * 4);
  float* coefIN  = (float*)alloc((size_t)N * CIN * 4);
  (void)ws_size; (void)n_in; (void)out_size;

  const int B = 256;
  hipLaunchKernelGGL(k_proj, dim3((N + B - 1) / B), dim3(B), 0, stream,
                     x, Wp, bp, gw0, hn, hnb, XWa, insum, indeg, N);
  hipLaunchKernelGGL(k_thresh, dim3(N / 4), dim3(B), 0, stream, hn, tau, N);
  hipLaunchKernelGGL(k_scan2, dim3((N / 16) * NC), dim3(B), 0, stream, hnb, tau, cnt, buf, N);
  hipLaunchKernelGGL(k_final, dim3(N / 4), dim3(B), 0, stream,
                     hn, buf, cnt, evals, eidx, ownsum, insum, indeg, incol, inval, N);

  // layer 0 (FIRST): computes + caches selfc/coefK/coefIN; epilogue XWb = h1 @ gw1
  hipLaunchKernelGGL((k_gpost32<20, 32, true>), dim3(N / 8), dim3(B), 0, stream,
                     XWa, eidx, evals, incol, inval, indeg, ownsum, insum,
                     selfc, coefK, coefIN,
                     gb0, lg0, lb0, x, riw0, rib0, riw1, rib1, gw1, XWb, h1, N);
  // layer 1: cached coefs; epilogue XWa = h2 @ gw2 (stride128)
  hipLaunchKernelGGL((k_gpost32<32, 128, false>), dim3(N / 8), dim3(B), 0, stream,
                     XWb, eidx, evals, incol, inval, indeg, ownsum, insum,
                     selfc, coefK, coefIN,
                     gb1, lg1, lb1, h1, rhw0, rhb0, rhw1, rhb1, gw2, XWa, h2, N);
  // layer 2: cached coefs, paired-column float2 layout
  hipLaunchKernelGGL(k_gpost128, dim3(N / 4), dim3(B), 0, stream,
                     XWa, eidx, coefK, incol, coefIN, indeg, selfc,
                     gb2, lg2, lb2, h2, row0, rob0, row1, rob1, out, N);
}

// Round 18
// 173.643 us; speedup vs baseline: 1.0004x; 1.0004x over previous
//
#include <hip/hip_runtime.h>

constexpr int D_IN = 20;   // input feature dim
constexpr int HP   = 16;   // projection dim
constexpr int K    = 6;    // neighbors
constexpr int SAMP = 512;  // threshold sample size
constexpr int NC   = 8;    // candidate chunks (segmented buffers)
constexpr int CAPC = 192;  // per-(row,chunk) buffer capacity
constexpr int CIN  = 128;  // per-row in-edge slots
constexpr float MARGIN = 0.02f;  // covers bf16-vs-fp32 dot error

typedef __attribute__((ext_vector_type(8))) short bf16x8;
typedef __attribute__((ext_vector_type(4))) float f32x4;

// Sequential fmaf dot — MUST be bit-identical across thresh/final.
__device__ __forceinline__ float dot16_seq(const float4* q, const float4* c) {
  float s = 0.f;
#pragma unroll
  for (int m = 0; m < 4; ++m) {
    s = fmaf(q[m].x, c[m].x, s);
    s = fmaf(q[m].y, c[m].y, s);
    s = fmaf(q[m].z, c[m].z, s);
    s = fmaf(q[m].w, c[m].w, s);
  }
  return s;
}

// round-to-nearest-even f32 -> bf16 bits
__device__ __forceinline__ short f2bf(float f) {
  unsigned u = __float_as_uint(f);
  unsigned r = (u + 0x7fffu + ((u >> 16) & 1u)) >> 16;
  return (short)r;
}

__device__ __forceinline__ float dinv_of(float own, float ins) {
  float rs = 0.5f * (own + ins);
  float rn = 1.f / (rs + 1e-8f);
  return rsqrtf(fmaxf(1.f + rs * rn, 1e-12f));
}

// ---- projection + row-normalize + bf16 copy + XW0 + counter zeroing ----
__global__ void k_proj(const float* __restrict__ x, const float* __restrict__ Wp,
                       const float* __restrict__ bp, const float* __restrict__ gw0,
                       float* __restrict__ hn, short* __restrict__ hnb,
                       float* __restrict__ XW0,
                       float* __restrict__ insum, int* __restrict__ indeg, int N) {
  int i = blockIdx.x * blockDim.x + threadIdx.x;
  if (i >= N) return;
  insum[i] = 0.f; indeg[i] = 0;
  float xr[D_IN];
#pragma unroll
  for (int d = 0; d < D_IN; ++d) xr[d] = x[i*D_IN + d];
  float hv[HP];
  float nrm2 = 0.f;
#pragma unroll
  for (int h = 0; h < HP; ++h) {
    float a = bp[h];
#pragma unroll
    for (int d = 0; d < D_IN; ++d) a += xr[d] * Wp[d*HP + h];
    hv[h] = a;
    nrm2 += a * a;
  }
  float inv = 1.f / fmaxf(sqrtf(nrm2), 1e-12f);
#pragma unroll
  for (int h = 0; h < HP; ++h) {
    float v = hv[h] * inv;
    hn[i*HP + h] = v;
    hnb[(size_t)i*32 + h] = f2bf(v);
  }
#pragma unroll
  for (int h = 0; h < HP; ++h) hnb[(size_t)i*32 + 16 + h] = 0;
#pragma unroll
  for (int oc = 0; oc < 32; ++oc) {
    float a = 0.f;
#pragma unroll
    for (int d = 0; d < D_IN; ++d) a += xr[d] * gw0[d*32 + oc];
    XW0[(size_t)i*32 + oc] = a;
  }
}

// ---------------- per-lane top-6 in NAMED registers ----
struct Top6 { float v0,v1,v2,v3,v4,v5; int i0,i1,i2,i3,i4,i5; };

__device__ __forceinline__ void t6_init(Top6& t) {
  t.v0=t.v1=t.v2=t.v3=t.v4=t.v5=-1e30f;
  t.i0=t.i1=t.i2=t.i3=t.i4=t.i5=-1;
}

#define T6_SWAP(a,b,ia,ib) { float tv=a; a=b; b=tv; int ti=ia; ia=ib; ib=ti; }

__device__ __forceinline__ void t6_insert(Top6& t, float s, int c) {
  if (s > t.v5) {
    t.v5 = s; t.i5 = c;
    if (t.v5 > t.v4) { T6_SWAP(t.v4, t.v5, t.i4, t.i5); }
    if (t.v4 > t.v3) { T6_SWAP(t.v3, t.v4, t.i3, t.i4); }
    if (t.v3 > t.v2) { T6_SWAP(t.v2, t.v3, t.i2, t.i3); }
    if (t.v2 > t.v1) { T6_SWAP(t.v1, t.v2, t.i1, t.i2); }
    if (t.v1 > t.v0) { T6_SWAP(t.v0, t.v1, t.i0, t.i1); }
  }
}

__device__ __forceinline__ void t6_best(const Top6& t, float& cv, int& ci) {
  cv = t.v0; ci = t.i0;
  if (t.v1 > cv || (t.v1 == cv && (unsigned)t.i1 < (unsigned)ci)) { cv = t.v1; ci = t.i1; }
  if (t.v2 > cv || (t.v2 == cv && (unsigned)t.i2 < (unsigned)ci)) { cv = t.v2; ci = t.i2; }
  if (t.v3 > cv || (t.v3 == cv && (unsigned)t.i3 < (unsigned)ci)) { cv = t.v3; ci = t.i3; }
  if (t.v4 > cv || (t.v4 == cv && (unsigned)t.i4 < (unsigned)ci)) { cv = t.v4; ci = t.i4; }
  if (t.v5 > cv || (t.v5 == cv && (unsigned)t.i5 < (unsigned)ci)) { cv = t.v5; ci = t.i5; }
}

__device__ __forceinline__ void t6_consume(Top6& t, int mi) {
  if (t.i0 == mi) t.v0 = -1e30f;
  if (t.i1 == mi) t.v1 = -1e30f;
  if (t.i2 == mi) t.v2 = -1e30f;
  if (t.i3 == mi) t.v3 = -1e30f;
  if (t.i4 == mi) t.v4 = -1e30f;
  if (t.i5 == mi) t.v5 = -1e30f;
}

// ---------------- threshold pass: exact 6th-largest over SAMP-sample, wave per row
__global__ __launch_bounds__(256) void k_thresh(const float* __restrict__ hn,
                                                float* __restrict__ tau, int N) {
  int wave = threadIdx.x >> 6, lane = threadIdx.x & 63;
  int row = blockIdx.x * 4 + wave;
  const float4* hn4 = (const float4*)hn;
  float4 q[4];
#pragma unroll
  for (int m = 0; m < 4; ++m) q[m] = hn4[(size_t)row*4 + m];
  Top6 t; t6_init(t);
#pragma unroll
  for (int k = 0; k < SAMP/64; ++k) {
    int c = lane + 64*k;
    if (c != row) {
      float4 cv[4];
#pragma unroll
      for (int m = 0; m < 4; ++m) cv[m] = hn4[(size_t)c*4 + m];
      float s = dot16_seq(q, cv);
      t6_insert(t, s, c);
    }
  }
  float last = -1e30f;
  for (int sel = 0; sel < K; ++sel) {
    float cv; int ci;
    t6_best(t, cv, ci);
    float mv = cv; int mi = ci;
#pragma unroll
    for (int m = 1; m < 64; m <<= 1) {
      float ov = __shfl_xor(mv, m);
      int   oi = __shfl_xor(mi, m);
      if (ov > mv || (ov == mv && (unsigned)oi < (unsigned)mi)) { mv = ov; mi = oi; }
    }
    t6_consume(t, mi);
    last = mv;
  }
  if (lane == 0) tau[row] = last;
}

// ---------------- MFMA threshold scan: segmented XCD-local appends ----------------
__global__ __launch_bounds__(256) void k_scan2(
    const short* __restrict__ hnb, const float* __restrict__ tau,
    int* __restrict__ cnt, unsigned short* __restrict__ buf, int N) {
  __shared__ int cntl[16];
  int rb = blockIdx.x / NC;          // row group
  int jc = blockIdx.x % NC;          // candidate chunk
  int wave = threadIdx.x >> 6, lane = threadIdx.x & 63;
  int r0 = rb * 16;
  int half = lane >> 4;              // 0..3
  int l16  = lane & 15;

  if (threadIdx.x < 16) cntl[threadIdx.x] = 0;
  __syncthreads();

  bf16x8 a = *(const bf16x8*)(hnb + (size_t)(r0 + l16)*32 + half*8);
  float4 t4 = *(const float4*)(tau + r0 + half*4);
  float tm0 = t4.x - MARGIN, tm1 = t4.y - MARGIN,
        tm2 = t4.z - MARGIN, tm3 = t4.w - MARGIN;
  f32x4 zero = {0.f, 0.f, 0.f, 0.f};

  const int SPANW = N / NC / 4;      // cands per wave (256)
  int jb0 = jc * (N / NC) + wave * SPANW;

#define APPB(R, COND)                                                        \
  {                                                                          \
    unsigned long long mr = __ballot(COND);                                  \
    if (l16 == 0) {                                                          \
      unsigned mask = (unsigned)(mr >> (16*half)) & 0xFFFFu;                 \
      if (mask) {                                                            \
        int row = r0 + half*4 + (R);                                         \
        int pos = atomicAdd(&cntl[4*half + (R)], __popc(mask));              \
        unsigned mm = mask;                                                  \
        while (mm) {                                                         \
          int bx = __ffs(mm) - 1; mm &= mm - 1;                              \
          if (pos < CAPC)                                                    \
            buf[((size_t)row*NC + jc)*CAPC + pos] = (unsigned short)(jb + bx); \
          ++pos;                                                             \
        }                                                                    \
      }                                                                      \
    }                                                                        \
  }

#pragma unroll 4
  for (int jt = 0; jt < SPANW; jt += 16) {
    int jb = jb0 + jt;
    bf16x8 b = *(const bf16x8*)(hnb + (size_t)(jb + l16)*32 + half*8);
    f32x4 d = __builtin_amdgcn_mfma_f32_16x16x32_bf16(a, b, zero, 0, 0, 0);
    bool h0 = d[0] >= tm0, h1 = d[1] >= tm1, h2 = d[2] >= tm2, h3 = d[3] >= tm3;
    if (__any(h0 | h1 | h2 | h3)) {
      APPB(0, h0) APPB(1, h1) APPB(2, h2) APPB(3, h3)
    }
  }
#undef APPB

  __syncthreads();
  if (threadIdx.x < 16)
    cnt[(size_t)(r0 + threadIdx.x)*NC + jc] = min(cntl[threadIdx.x], CAPC);
}

// ---- exact top-6 (flattened segments) + direct in-edge slot writes, wave per row --
__global__ __launch_bounds__(256) void k_final(
    const float* __restrict__ hn, const unsigned short* __restrict__ buf,
    const int* __restrict__ cnt,
    float* __restrict__ evals, int* __restrict__ eidx,
    float* __restrict__ ownsum, float* insum, int* indeg,
    unsigned short* __restrict__ incol, float* __restrict__ inval, int N) {
  int wave = threadIdx.x >> 6, lane = threadIdx.x & 63;
  int row = blockIdx.x * 4 + wave;
  const float4* hn4 = (const float4*)hn;
  float4 q[4];
#pragma unroll
  for (int m = 0; m < 4; ++m) q[m] = hn4[(size_t)row*4 + m];

  int cbase = row * NC;
  int cl = (lane < NC) ? cnt[cbase + lane] : 0;
  int c0 = __shfl(cl, 0), c1 = __shfl(cl, 1), c2 = __shfl(cl, 2), c3 = __shfl(cl, 3),
      c4 = __shfl(cl, 4), c5 = __shfl(cl, 5), c6 = __shfl(cl, 6), c7 = __shfl(cl, 7);
  int p1 = c0, p2 = p1 + c1, p3 = p2 + c2, p4 = p3 + c3,
      p5 = p4 + c4, p6 = p5 + c5, p7 = p6 + c6, T = p7 + c7;

  Top6 t; t6_init(t);
  for (int e = lane; e < T; e += 64) {
    int s, off;
    if (e < p4) {
      if (e < p2) { if (e < p1) { s = 0; off = e; } else { s = 1; off = e - p1; } }
      else        { if (e < p3) { s = 2; off = e - p2; } else { s = 3; off = e - p3; } }
    } else {
      if (e < p6) { if (e < p5) { s = 4; off = e - p4; } else { s = 5; off = e - p5; } }
      else        { if (e < p7) { s = 6; off = e - p6; } else { s = 7; off = e - p7; } }
    }
    int j = buf[((size_t)cbase + s)*CAPC + off];
    if (j != row) {
      float4 cv[4];
#pragma unroll
      for (int m = 0; m < 4; ++m) cv[m] = hn4[(size_t)j*4 + m];
      float sc = dot16_seq(q, cv);
      t6_insert(t, sc, j);
    }
  }
  float osum = 0.f;
  for (int sel = 0; sel < K; ++sel) {
    float cv; int ci;
    t6_best(t, cv, ci);
    float mv = cv; int mi = ci;
#pragma unroll
    for (int m = 1; m < 64; m <<= 1) {
      float ov = __shfl_xor(mv, m);
      int   oi = __shfl_xor(mi, m);
      if (ov > mv || (ov == mv && (unsigned)oi < (unsigned)mi)) { mv = ov; mi = oi; }
    }
    t6_consume(t, mi);
    if (lane == 0) {
      evals[row*K + sel] = mv;
      eidx [row*K + sel] = mi;
      osum += mv;
      atomicAdd(&insum[mi], mv);
      int pos = atomicAdd(&indeg[mi], 1);
      if (pos < CIN) {
        incol[(size_t)mi*CIN + pos] = (unsigned short)row;
        inval[(size_t)mi*CIN + pos] = mv;
      }
    }
  }
  if (lane == 0) ownsum[row] = osum;
}

// ---- DOUT=32 layer: GCN + LN + ReLU + MLP residual, 2 rows/wave.
// FIRST=true: compute coefficients from ownsum/insum/evals and CACHE them
// (selfc, coefK, coefIN) for the later layers. FIRST=false: load cached coefs.
// Epilogue computes next layer's XW row-locally (h shared via LDS).
template<int DIN, int NEXTD, bool FIRST>
__global__ __launch_bounds__(256) void k_gpost32(
    const float* __restrict__ XWsrc,
    const int* __restrict__ eidx, const float* __restrict__ evals,
    const unsigned short* __restrict__ incol, const float* __restrict__ inval,
    const int* __restrict__ indeg,
    const float* __restrict__ ownsum, const float* __restrict__ insum,
    float* __restrict__ selfc, float* __restrict__ coefK, float* __restrict__ coefIN,
    const float* __restrict__ gb, const float* __restrict__ lg, const float* __restrict__ lb,
    const float* __restrict__ hprev,
    const float* __restrict__ w0, const float* __restrict__ b0,
    const float* __restrict__ w1, const float* __restrict__ b1,
    const float* __restrict__ Wnext, float* __restrict__ XWnext,
    float* __restrict__ outp, int N) {
  __shared__ float hid[4][2][32];
  int tid = threadIdx.x;
  int lane = tid & 63, wslot = tid >> 6;
  int sub = lane >> 5, ol = lane & 31;
  int row = (blockIdx.x * 4 + wslot) * 2 + sub;

  float acc;
  int ne = min(indeg[row], CIN);
  if constexpr (FIRST) {
    float rs_i = 0.5f * (ownsum[row] + insum[row]);
    float rn_i = 1.f / (rs_i + 1e-8f);
    float di_i = rsqrtf(fmaxf(1.f + rs_i * rn_i, 1e-12f));
    float cc = 0.5f * di_i * rn_i;
    float sc = di_i * di_i;
    if (ol == 0) selfc[row] = sc;
    acc = sc * XWsrc[(size_t)row*32 + ol];
#pragma unroll
    for (int t = 0; t < K; ++t) {
      int j = eidx[row*K + t]; float v = evals[row*K + t];
      float dj = dinv_of(ownsum[j], insum[j]);
      float cf = cc * v * dj;
      if (ol == 0) coefK[row*K + t] = cf;
      acc = fmaf(cf, XWsrc[(size_t)j*32 + ol], acc);
    }
    for (int e = 0; e < ne; ++e) {
      int j = incol[(size_t)row*CIN + e]; float v = inval[(size_t)row*CIN + e];
      float dj = dinv_of(ownsum[j], insum[j]);
      float cf = cc * v * dj;
      if (ol == 0) coefIN[(size_t)row*CIN + e] = cf;
      acc = fmaf(cf, XWsrc[(size_t)j*32 + ol], acc);
    }
  } else {
    acc = selfc[row] * XWsrc[(size_t)row*32 + ol];
#pragma unroll
    for (int t = 0; t < K; ++t) {
      int j = eidx[row*K + t]; float cf = coefK[row*K + t];
      acc = fmaf(cf, XWsrc[(size_t)j*32 + ol], acc);
    }
    const unsigned short* icp = incol + (size_t)row*CIN;
    const float* cfp = coefIN + (size_t)row*CIN;
    for (int e0 = 0; e0 < ne; e0 += 4) {
      int j0 = icp[e0];                          float cf0 = cfp[e0];
      int b1v = e0+1 < ne, b2v = e0+2 < ne, b3v = e0+3 < ne;
      int j1 = b1v ? icp[e0+1] : j0;             float cf1 = b1v ? cfp[e0+1] : 0.f;
      int j2 = b2v ? icp[e0+2] : j0;             float cf2 = b2v ? cfp[e0+2] : 0.f;
      int j3 = b3v ? icp[e0+3] : j0;             float cf3 = b3v ? cfp[e0+3] : 0.f;
      float v0 = XWsrc[(size_t)j0*32 + ol], v1 = XWsrc[(size_t)j1*32 + ol],
            v2 = XWsrc[(size_t)j2*32 + ol], v3 = XWsrc[(size_t)j3*32 + ol];
      acc = fmaf(cf0, v0, acc);
      acc = fmaf(cf1, v1, acc);
      acc = fmaf(cf2, v2, acc);
      acc = fmaf(cf3, v3, acc);
    }
  }
  float u0 = acc + gb[ol];
  float s = u0;
#pragma unroll
  for (int m = 1; m < 32; m <<= 1) s += __shfl_xor(s, m);
  float mean = s * (1.f/32.f);
  float d0 = u0 - mean;
  float vs = d0*d0;
#pragma unroll
  for (int m = 1; m < 32; m <<= 1) vs += __shfl_xor(vs, m);
  float rstd = rsqrtf(vs * (1.f/32.f) + 1e-5f);
  float t0 = fmaxf(d0*rstd*lg[ol] + lb[ol], 0.f);

  // MLP residual (per-wave LDS; same-wave lockstep -> no barrier)
  float hp[DIN];
#pragma unroll
  for (int d = 0; d < DIN; ++d) hp[d] = hprev[(size_t)row*DIN + d];
  float a = b0[ol];
#pragma unroll
  for (int d = 0; d < DIN; ++d) a = fmaf(hp[d], w0[d*32 + ol], a);
  hid[wslot][sub][ol] = fmaxf(a, 0.f);
  // w1 product with ILP-4 partials (chain 32 -> 8)
  float r0 = 0.f, r1 = 0.f, r2 = 0.f, r3 = 0.f;
#pragma unroll
  for (int h = 0; h < 32; h += 4) {
    r0 = fmaf(hid[wslot][sub][h+0], w1[(h+0)*32 + ol], r0);
    r1 = fmaf(hid[wslot][sub][h+1], w1[(h+1)*32 + ol], r1);
    r2 = fmaf(hid[wslot][sub][h+2], w1[(h+2)*32 + ol], r2);
    r3 = fmaf(hid[wslot][sub][h+3], w1[(h+3)*32 + ol], r3);
  }
  float hv = t0 + b1[ol] + ((r0 + r1) + (r2 + r3));
  outp[(size_t)row*32 + ol] = hv;

  // epilogue: XWnext = h @ Wnext (h row shared via LDS), ILP-4
  hid[wslot][sub][ol] = hv;
#pragma unroll
  for (int k2 = 0; k2 < NEXTD/32; ++k2) {
    int oc = ol + 32*k2;
    float e0 = 0.f, e1 = 0.f, e2 = 0.f, e3 = 0.f;
#pragma unroll
    for (int d = 0; d < 32; d += 4) {
      e0 = fmaf(hid[wslot][sub][d+0], Wnext[(d+0)*NEXTD + oc], e0);
      e1 = fmaf(hid[wslot][sub][d+1], Wnext[(d+1)*NEXTD + oc], e1);
      e2 = fmaf(hid[wslot][sub][d+2], Wnext[(d+2)*NEXTD + oc], e2);
      e3 = fmaf(hid[wslot][sub][d+3], Wnext[(d+3)*NEXTD + oc], e3);
    }
    XWnext[(size_t)row*NEXTD + oc] = (e0 + e1) + (e2 + e3);
  }
}

// ---------------- final layer (DOUT=128): paired-column float2 layout ----
// lane owns cols (2*lane, 2*lane+1): every XW/w0/w1/out access is one float2.
__global__ __launch_bounds__(256) void k_gpost128(
    const float* __restrict__ XW,
    const int* __restrict__ eidx, const float* __restrict__ coefK,
    const unsigned short* __restrict__ incol, const float* __restrict__ coefIN,
    const int* __restrict__ indeg, const float* __restrict__ selfc,
    const float* __restrict__ b, const float* __restrict__ g, const float* __restrict__ bt,
    const float* __restrict__ hprev,
    const float* __restrict__ w0, const float* __restrict__ b0,
    const float* __restrict__ w1, const float* __restrict__ b1,
    float* __restrict__ out, int N) {
  __shared__ float hid_s[4][128];
  int wslot = threadIdx.x >> 6;
  int row   = (blockIdx.x * blockDim.x + threadIdx.x) >> 6;
  int lane  = threadIdx.x & 63;
  const float2* XW2 = (const float2*)XW;   // row stride 64 float2

  float sc = selfc[row];
  float2 xs = XW2[(size_t)row*64 + lane];
  float acc0 = sc * xs.x, acc1 = sc * xs.y;
#pragma unroll
  for (int t = 0; t < K; ++t) {
    int j = eidx[row*K + t]; float cf = coefK[row*K + t];
    float2 v = XW2[(size_t)j*64 + lane];
    acc0 = fmaf(cf, v.x, acc0); acc1 = fmaf(cf, v.y, acc1);
  }
  int ne = min(indeg[row], CIN);
  const unsigned short* icp = incol + (size_t)row*CIN;
  const float* cfp = coefIN + (size_t)row*CIN;
  for (int e0 = 0; e0 < ne; e0 += 4) {
    int j0 = icp[e0];                      float c0 = cfp[e0];
    int b1v = e0+1 < ne, b2v = e0+2 < ne, b3v = e0+3 < ne;
    int j1 = b1v ? icp[e0+1] : j0;         float c1 = b1v ? cfp[e0+1] : 0.f;
    int j2 = b2v ? icp[e0+2] : j0;         float c2 = b2v ? cfp[e0+2] : 0.f;
    int j3 = b3v ? icp[e0+3] : j0;         float c3 = b3v ? cfp[e0+3] : 0.f;
    float2 v0 = XW2[(size_t)j0*64 + lane], v1 = XW2[(size_t)j1*64 + lane],
           v2 = XW2[(size_t)j2*64 + lane], v3 = XW2[(size_t)j3*64 + lane];
    acc0 = fmaf(c0, v0.x, acc0); acc1 = fmaf(c0, v0.y, acc1);
    acc0 = fmaf(c1, v1.x, acc0); acc1 = fmaf(c1, v1.y, acc1);
    acc0 = fmaf(c2, v2.x, acc0); acc1 = fmaf(c2, v2.y, acc1);
    acc0 = fmaf(c3, v3.x, acc0); acc1 = fmaf(c3, v3.y, acc1);
  }
  float2 bv = ((const float2*)b)[lane];
  float u0 = acc0 + bv.x, u1 = acc1 + bv.y;

  float s = u0 + u1;
#pragma unroll
  for (int m = 1; m < 64; m <<= 1) s += __shfl_xor(s, m);
  float mean = s * (1.f/128.f);
  float d0 = u0 - mean, d1 = u1 - mean;
  float vs = d0*d0 + d1*d1;
#pragma unroll
  for (int m = 1; m < 64; m <<= 1) vs += __shfl_xor(vs, m);
  float rstd = rsqrtf(vs * (1.f/128.f) + 1e-5f);
  float2 gv = ((const float2*)g)[lane], btv = ((const float2*)bt)[lane];
  float t0 = fmaxf(d0*rstd*gv.x + btv.x, 0.f);
  float t1 = fmaxf(d1*rstd*gv.y + btv.y, 0.f);

  float hp[32];
#pragma unroll
  for (int d = 0; d < 32; ++d) hp[d] = hprev[(size_t)row*32 + d];
  const float2* w02 = (const float2*)w0;   // row stride 64 float2
  float2 b0v = ((const float2*)b0)[lane];
  float a0 = b0v.x, a1 = b0v.y;
#pragma unroll
  for (int d = 0; d < 32; ++d) {
    float2 wv = w02[(size_t)d*64 + lane];
    a0 = fmaf(hp[d], wv.x, a0);
    a1 = fmaf(hp[d], wv.y, a1);
  }
  ((float2*)hid_s[wslot])[lane] = make_float2(fmaxf(a0, 0.f), fmaxf(a1, 0.f));
  __syncthreads();

  // out = hid @ w1: float2 loads + ILP-4 partials (chain 128 -> 32)
  const float2* w12 = (const float2*)w1;
  float r0=0.f, r1=0.f, r2=0.f, r3=0.f, q0=0.f, q1=0.f, q2=0.f, q3=0.f;
#pragma unroll
  for (int h = 0; h < 128; h += 4) {
    float h0 = hid_s[wslot][h+0], h1 = hid_s[wslot][h+1],
          h2 = hid_s[wslot][h+2], h3 = hid_s[wslot][h+3];
    float2 wa = w12[(size_t)(h+0)*64 + lane];
    float2 wb = w12[(size_t)(h+1)*64 + lane];
    float2 wc = w12[(size_t)(h+2)*64 + lane];
    float2 wd = w12[(size_t)(h+3)*64 + lane];
    r0 = fmaf(h0, wa.x, r0); q0 = fmaf(h0, wa.y, q0);
    r1 = fmaf(h1, wb.x, r1); q1 = fmaf(h1, wb.y, q1);
    r2 = fmaf(h2, wc.x, r2); q2 = fmaf(h2, wc.y, q2);
    r3 = fmaf(h3, wd.x, r3); q3 = fmaf(h3, wd.y, q3);
  }
  float2 b1v = ((const float2*)b1)[lane];
  float ox = t0 + b1v.x + ((r0 + r1) + (r2 + r3));
  float oy = t1 + b1v.y + ((q0 + q1) + (q2 + q3));
  ((float2*)out)[(size_t)row*64 + lane] = make_float2(ox, oy);
}

extern "C" void kernel_launch(void* const* d_in, const int* in_sizes, int n_in,
                              void* d_out, int out_size, void* d_ws, size_t ws_size,
                              hipStream_t stream) {
  const float* x    = (const float*)d_in[0];
  const float* Wp   = (const float*)d_in[1];
  const float* bp   = (const float*)d_in[2];
  const float* gw0  = (const float*)d_in[3];
  const float* gb0  = (const float*)d_in[4];
  const float* gw1  = (const float*)d_in[5];
  const float* gb1  = (const float*)d_in[6];
  const float* gw2  = (const float*)d_in[7];
  const float* gb2  = (const float*)d_in[8];
  const float* lg0  = (const float*)d_in[9];
  const float* lb0  = (const float*)d_in[10];
  const float* lg1  = (const float*)d_in[11];
  const float* lb1  = (const float*)d_in[12];
  const float* lg2  = (const float*)d_in[13];
  const float* lb2  = (const float*)d_in[14];
  const float* riw0 = (const float*)d_in[15];
  const float* rib0 = (const float*)d_in[16];
  const float* riw1 = (const float*)d_in[17];
  const float* rib1 = (const float*)d_in[18];
  const float* rhw0 = (const float*)d_in[19];
  const float* rhb0 = (const float*)d_in[20];
  const float* rhw1 = (const float*)d_in[21];
  const float* rhb1 = (const float*)d_in[22];
  const float* row0 = (const float*)d_in[23];
  const float* rob0 = (const float*)d_in[24];
  const float* row1 = (const float*)d_in[25];
  const float* rob1 = (const float*)d_in[26];
  int N = in_sizes[0] / D_IN;   // 8192
  float* out = (float*)d_out;

  char* ws = (char*)d_ws;
  size_t off = 0;
  auto alloc = [&](size_t bytes) -> void* {
    void* p = ws + off;
    off += (bytes + 255) & ~(size_t)255;
    return p;
  };
  float* hn      = (float*)alloc((size_t)N * HP * 4);
  float* evals   = (float*)alloc((size_t)N * K * 4);
  int*   eidx    = (int*)  alloc((size_t)N * K * 4);
  float* ownsum  = (float*)alloc((size_t)N * 4);
  float* insum   = (float*)alloc((size_t)N * 4);
  int*   indeg   = (int*)  alloc((size_t)N * 4);
  float* XWa     = (float*)alloc((size_t)N * 128 * 4);
  float* XWb     = (float*)alloc((size_t)N * 32 * 4);
  float* h1      = (float*)alloc((size_t)N * 32 * 4);
  float* h2      = (float*)alloc((size_t)N * 32 * 4);
  float* tau     = (float*)alloc((size_t)N * 4);
  int*   cnt     = (int*)  alloc((size_t)N * NC * 4);
  unsigned short* buf = (unsigned short*)alloc((size_t)N * NC * CAPC * 2);
  short* hnb     = (short*)alloc((size_t)N * 32 * 2);
  unsigned short* incol = (unsigned short*)alloc((size_t)N * CIN * 2);
  float* inval   = (float*)alloc((size_t)N * CIN * 4);
  float* selfc   = (float*)alloc((size_t)N * 4);
  float* coefK   = (float*)alloc((size_t)N * K * 4);
  float* coefIN  = (float*)alloc((size_t)N * CIN * 4);
  (void)ws_size; (void)n_in; (void)out_size;

  const int B = 256;
  hipLaunchKernelGGL(k_proj, dim3((N + B - 1) / B), dim3(B), 0, stream,
                     x, Wp, bp, gw0, hn, hnb, XWa, insum, indeg, N);
  hipLaunchKernelGGL(k_thresh, dim3(N / 4), dim3(B), 0, stream, hn, tau, N);
  hipLaunchKernelGGL(k_scan2, dim3((N / 16) * NC), dim3(B), 0, stream, hnb, tau, cnt, buf, N);
  hipLaunchKernelGGL(k_final, dim3(N / 4), dim3(B), 0, stream,
                     hn, buf, cnt, evals, eidx, ownsum, insum, indeg, incol, inval, N);

  // layer 0 (FIRST): computes + caches selfc/coefK/coefIN; epilogue XWb = h1 @ gw1
  hipLaunchKernelGGL((k_gpost32<20, 32, true>), dim3(N / 8), dim3(B), 0, stream,
                     XWa, eidx, evals, incol, inval, indeg, ownsum, insum,
                     selfc, coefK, coefIN,
                     gb0, lg0, lb0, x, riw0, rib0, riw1, rib1, gw1, XWb, h1, N);
  // layer 1: cached coefs; epilogue XWa = h2 @ gw2 (stride128)
  hipLaunchKernelGGL((k_gpost32<32, 128, false>), dim3(N / 8), dim3(B), 0, stream,
                     XWb, eidx, evals, incol, inval, indeg, ownsum, insum,
                     selfc, coefK, coefIN,
                     gb1, lg1, lb1, h1, rhw0, rhb0, rhw1, rhb1, gw2, XWa, h2, N);
  // layer 2: cached coefs, paired-column float2 layout
  hipLaunchKernelGGL(k_gpost128, dim3(N / 4), dim3(B), 0, stream,
                     XWa, eidx, coefK, incol, coefIN, indeg, selfc,
                     gb2, lg2, lb2, h2, row0, rob0, row1, rob1, out, N);
}

// Round 19
// 153.924 us; speedup vs baseline: 1.1285x; 1.1281x over previous
//
#include <hip/hip_runtime.h>

constexpr int D_IN = 20;   // input feature dim
constexpr int HP   = 16;   // projection dim
constexpr int K    = 6;    // neighbors
constexpr int SAMP = 512;  // threshold sample size
constexpr int NC   = 8;    // candidate chunks (segmented buffers)
constexpr int CAPC = 192;  // per-(row,chunk) buffer capacity
constexpr int CIN  = 128;  // per-row in-edge slots
constexpr float MARGIN = 0.02f;  // covers bf16-vs-fp32 dot error

typedef __attribute__((ext_vector_type(8))) short bf16x8;
typedef __attribute__((ext_vector_type(4))) float f32x4;

// Sequential fmaf dot — MUST be bit-identical across thresh/final.
__device__ __forceinline__ float dot16_seq(const float4* q, const float4* c) {
  float s = 0.f;
#pragma unroll
  for (int m = 0; m < 4; ++m) {
    s = fmaf(q[m].x, c[m].x, s);
    s = fmaf(q[m].y, c[m].y, s);
    s = fmaf(q[m].z, c[m].z, s);
    s = fmaf(q[m].w, c[m].w, s);
  }
  return s;
}

// round-to-nearest-even f32 -> bf16 bits
__device__ __forceinline__ short f2bf(float f) {
  unsigned u = __float_as_uint(f);
  unsigned r = (u + 0x7fffu + ((u >> 16) & 1u)) >> 16;
  return (short)r;
}

__device__ __forceinline__ float dinv_of(float own, float ins) {
  float rs = 0.5f * (own + ins);
  float rn = 1.f / (rs + 1e-8f);
  return rsqrtf(fmaxf(1.f + rs * rn, 1e-12f));
}

// ---- projection + row-normalize + bf16 copy + XW0 + counter zeroing ----
__global__ void k_proj(const float* __restrict__ x, const float* __restrict__ Wp,
                       const float* __restrict__ bp, const float* __restrict__ gw0,
                       float* __restrict__ hn, short* __restrict__ hnb,
                       float* __restrict__ XW0,
                       float* __restrict__ insum, int* __restrict__ indeg, int N) {
  int i = blockIdx.x * blockDim.x + threadIdx.x;
  if (i >= N) return;
  insum[i] = 0.f; indeg[i] = 0;
  float xr[D_IN];
#pragma unroll
  for (int d = 0; d < D_IN; ++d) xr[d] = x[i*D_IN + d];
  float hv[HP];
  float nrm2 = 0.f;
#pragma unroll
  for (int h = 0; h < HP; ++h) {
    float a = bp[h];
#pragma unroll
    for (int d = 0; d < D_IN; ++d) a += xr[d] * Wp[d*HP + h];
    hv[h] = a;
    nrm2 += a * a;
  }
  float inv = 1.f / fmaxf(sqrtf(nrm2), 1e-12f);
#pragma unroll
  for (int h = 0; h < HP; ++h) {
    float v = hv[h] * inv;
    hn[i*HP + h] = v;
    hnb[(size_t)i*32 + h] = f2bf(v);
  }
#pragma unroll
  for (int h = 0; h < HP; ++h) hnb[(size_t)i*32 + 16 + h] = 0;
#pragma unroll
  for (int oc = 0; oc < 32; ++oc) {
    float a = 0.f;
#pragma unroll
    for (int d = 0; d < D_IN; ++d) a += xr[d] * gw0[d*32 + oc];
    XW0[(size_t)i*32 + oc] = a;
  }
}

// ---------------- per-lane top-6 in NAMED registers ----
struct Top6 { float v0,v1,v2,v3,v4,v5; int i0,i1,i2,i3,i4,i5; };

__device__ __forceinline__ void t6_init(Top6& t) {
  t.v0=t.v1=t.v2=t.v3=t.v4=t.v5=-1e30f;
  t.i0=t.i1=t.i2=t.i3=t.i4=t.i5=-1;
}

#define T6_SWAP(a,b,ia,ib) { float tv=a; a=b; b=tv; int ti=ia; ia=ib; ib=ti; }

__device__ __forceinline__ void t6_insert(Top6& t, float s, int c) {
  if (s > t.v5) {
    t.v5 = s; t.i5 = c;
    if (t.v5 > t.v4) { T6_SWAP(t.v4, t.v5, t.i4, t.i5); }
    if (t.v4 > t.v3) { T6_SWAP(t.v3, t.v4, t.i3, t.i4); }
    if (t.v3 > t.v2) { T6_SWAP(t.v2, t.v3, t.i2, t.i3); }
    if (t.v2 > t.v1) { T6_SWAP(t.v1, t.v2, t.i1, t.i2); }
    if (t.v1 > t.v0) { T6_SWAP(t.v0, t.v1, t.i0, t.i1); }
  }
}

__device__ __forceinline__ void t6_best(const Top6& t, float& cv, int& ci) {
  cv = t.v0; ci = t.i0;
  if (t.v1 > cv || (t.v1 == cv && (unsigned)t.i1 < (unsigned)ci)) { cv = t.v1; ci = t.i1; }
  if (t.v2 > cv || (t.v2 == cv && (unsigned)t.i2 < (unsigned)ci)) { cv = t.v2; ci = t.i2; }
  if (t.v3 > cv || (t.v3 == cv && (unsigned)t.i3 < (unsigned)ci)) { cv = t.v3; ci = t.i3; }
  if (t.v4 > cv || (t.v4 == cv && (unsigned)t.i4 < (unsigned)ci)) { cv = t.v4; ci = t.i4; }
  if (t.v5 > cv || (t.v5 == cv && (unsigned)t.i5 < (unsigned)ci)) { cv = t.v5; ci = t.i5; }
}

__device__ __forceinline__ void t6_consume(Top6& t, int mi) {
  if (t.i0 == mi) t.v0 = -1e30f;
  if (t.i1 == mi) t.v1 = -1e30f;
  if (t.i2 == mi) t.v2 = -1e30f;
  if (t.i3 == mi) t.v3 = -1e30f;
  if (t.i4 == mi) t.v4 = -1e30f;
  if (t.i5 == mi) t.v5 = -1e30f;
}

// ---------------- threshold pass: exact 6th-largest over SAMP-sample, wave per row
__global__ __launch_bounds__(256) void k_thresh(const float* __restrict__ hn,
                                                float* __restrict__ tau, int N) {
  int wave = threadIdx.x >> 6, lane = threadIdx.x & 63;
  int row = blockIdx.x * 4 + wave;
  const float4* hn4 = (const float4*)hn;
  float4 q[4];
#pragma unroll
  for (int m = 0; m < 4; ++m) q[m] = hn4[(size_t)row*4 + m];
  Top6 t; t6_init(t);
#pragma unroll
  for (int k = 0; k < SAMP/64; ++k) {
    int c = lane + 64*k;
    if (c != row) {
      float4 cv[4];
#pragma unroll
      for (int m = 0; m < 4; ++m) cv[m] = hn4[(size_t)c*4 + m];
      float s = dot16_seq(q, cv);
      t6_insert(t, s, c);
    }
  }
  float last = -1e30f;
  for (int sel = 0; sel < K; ++sel) {
    float cv; int ci;
    t6_best(t, cv, ci);
    float mv = cv; int mi = ci;
#pragma unroll
    for (int m = 1; m < 64; m <<= 1) {
      float ov = __shfl_xor(mv, m);
      int   oi = __shfl_xor(mi, m);
      if (ov > mv || (ov == mv && (unsigned)oi < (unsigned)mi)) { mv = ov; mi = oi; }
    }
    t6_consume(t, mi);
    last = mv;
  }
  if (lane == 0) tau[row] = last;
}

// ---------------- MFMA threshold scan: segmented XCD-local appends ----------------
__global__ __launch_bounds__(256) void k_scan2(
    const short* __restrict__ hnb, const float* __restrict__ tau,
    int* __restrict__ cnt, unsigned short* __restrict__ buf, int N) {
  __shared__ int cntl[16];
  int rb = blockIdx.x / NC;          // row group
  int jc = blockIdx.x % NC;          // candidate chunk
  int wave = threadIdx.x >> 6, lane = threadIdx.x & 63;
  int r0 = rb * 16;
  int half = lane >> 4;              // 0..3
  int l16  = lane & 15;

  if (threadIdx.x < 16) cntl[threadIdx.x] = 0;
  __syncthreads();

  bf16x8 a = *(const bf16x8*)(hnb + (size_t)(r0 + l16)*32 + half*8);
  float4 t4 = *(const float4*)(tau + r0 + half*4);
  float tm0 = t4.x - MARGIN, tm1 = t4.y - MARGIN,
        tm2 = t4.z - MARGIN, tm3 = t4.w - MARGIN;
  f32x4 zero = {0.f, 0.f, 0.f, 0.f};

  const int SPANW = N / NC / 4;      // cands per wave (256)
  int jb0 = jc * (N / NC) + wave * SPANW;

#define APPB(R, COND)                                                        \
  {                                                                          \
    unsigned long long mr = __ballot(COND);                                  \
    if (l16 == 0) {                                                          \
      unsigned mask = (unsigned)(mr >> (16*half)) & 0xFFFFu;                 \
      if (mask) {                                                            \
        int row = r0 + half*4 + (R);                                         \
        int pos = atomicAdd(&cntl[4*half + (R)], __popc(mask));              \
        unsigned mm = mask;                                                  \
        while (mm) {                                                         \
          int bx = __ffs(mm) - 1; mm &= mm - 1;                              \
          if (pos < CAPC)                                                    \
            buf[((size_t)row*NC + jc)*CAPC + pos] = (unsigned short)(jb + bx); \
          ++pos;                                                             \
        }                                                                    \
      }                                                                      \
    }                                                                        \
  }

#pragma unroll 4
  for (int jt = 0; jt < SPANW; jt += 16) {
    int jb = jb0 + jt;
    bf16x8 b = *(const bf16x8*)(hnb + (size_t)(jb + l16)*32 + half*8);
    f32x4 d = __builtin_amdgcn_mfma_f32_16x16x32_bf16(a, b, zero, 0, 0, 0);
    bool h0 = d[0] >= tm0, h1 = d[1] >= tm1, h2 = d[2] >= tm2, h3 = d[3] >= tm3;
    if (__any(h0 | h1 | h2 | h3)) {
      APPB(0, h0) APPB(1, h1) APPB(2, h2) APPB(3, h3)
    }
  }
#undef APPB

  __syncthreads();
  if (threadIdx.x < 16)
    cnt[(size_t)(r0 + threadIdx.x)*NC + jc] = min(cntl[threadIdx.x], CAPC);
}

// ---- exact top-6 (flattened segments) + direct in-edge slot writes, wave per row --
__global__ __launch_bounds__(256) void k_final(
    const float* __restrict__ hn, const unsigned short* __restrict__ buf,
    const int* __restrict__ cnt,
    float* __restrict__ evals, int* __restrict__ eidx,
    float* __restrict__ ownsum, float* insum, int* indeg,
    unsigned short* __restrict__ incol, float* __restrict__ inval, int N) {
  int wave = threadIdx.x >> 6, lane = threadIdx.x & 63;
  int row = blockIdx.x * 4 + wave;
  const float4* hn4 = (const float4*)hn;
  float4 q[4];
#pragma unroll
  for (int m = 0; m < 4; ++m) q[m] = hn4[(size_t)row*4 + m];

  int cbase = row * NC;
  int cl = (lane < NC) ? cnt[cbase + lane] : 0;
  int c0 = __shfl(cl, 0), c1 = __shfl(cl, 1), c2 = __shfl(cl, 2), c3 = __shfl(cl, 3),
      c4 = __shfl(cl, 4), c5 = __shfl(cl, 5), c6 = __shfl(cl, 6), c7 = __shfl(cl, 7);
  int p1 = c0, p2 = p1 + c1, p3 = p2 + c2, p4 = p3 + c3,
      p5 = p4 + c4, p6 = p5 + c5, p7 = p6 + c6, T = p7 + c7;

  Top6 t; t6_init(t);
  for (int e = lane; e < T; e += 64) {
    int s, off;
    if (e < p4) {
      if (e < p2) { if (e < p1) { s = 0; off = e; } else { s = 1; off = e - p1; } }
      else        { if (e < p3) { s = 2; off = e - p2; } else { s = 3; off = e - p3; } }
    } else {
      if (e < p6) { if (e < p5) { s = 4; off = e - p4; } else { s = 5; off = e - p5; } }
      else        { if (e < p7) { s = 6; off = e - p6; } else { s = 7; off = e - p7; } }
    }
    int j = buf[((size_t)cbase + s)*CAPC + off];
    if (j != row) {
      float4 cv[4];
#pragma unroll
      for (int m = 0; m < 4; ++m) cv[m] = hn4[(size_t)j*4 + m];
      float sc = dot16_seq(q, cv);
      t6_insert(t, sc, j);
    }
  }
  float osum = 0.f;
  for (int sel = 0; sel < K; ++sel) {
    float cv; int ci;
    t6_best(t, cv, ci);
    float mv = cv; int mi = ci;
#pragma unroll
    for (int m = 1; m < 64; m <<= 1) {
      float ov = __shfl_xor(mv, m);
      int   oi = __shfl_xor(mi, m);
      if (ov > mv || (ov == mv && (unsigned)oi < (unsigned)mi)) { mv = ov; mi = oi; }
    }
    t6_consume(t, mi);
    if (lane == 0) {
      evals[row*K + sel] = mv;
      eidx [row*K + sel] = mi;
      osum += mv;
      atomicAdd(&insum[mi], mv);
      int pos = atomicAdd(&indeg[mi], 1);
      if (pos < CIN) {
        incol[(size_t)mi*CIN + pos] = (unsigned short)row;
        inval[(size_t)mi*CIN + pos] = mv;
      }
    }
  }
  if (lane == 0) ownsum[row] = osum;
}

// ---- DOUT=32 layer: GCN (inline coef) + LN + ReLU + MLP residual, 2 rows/wave,
// ---- epilogue computes next layer's XW row-locally (h shared via LDS).
template<int DIN, int NEXTD>
__global__ __launch_bounds__(256) void k_gpost32(
    const float* __restrict__ XWsrc,
    const int* __restrict__ eidx, const float* __restrict__ evals,
    const unsigned short* __restrict__ incol, const float* __restrict__ inval,
    const int* __restrict__ indeg,
    const float* __restrict__ ownsum, const float* __restrict__ insum,
    const float* __restrict__ gb, const float* __restrict__ lg, const float* __restrict__ lb,
    const float* __restrict__ hprev,
    const float* __restrict__ w0, const float* __restrict__ b0,
    const float* __restrict__ w1, const float* __restrict__ b1,
    const float* __restrict__ Wnext, float* __restrict__ XWnext,
    float* __restrict__ outp, int N) {
  __shared__ float hid[4][2][32];
  int tid = threadIdx.x;
  int lane = tid & 63, wslot = tid >> 6;
  int sub = lane >> 5, ol = lane & 31;
  int row = (blockIdx.x * 4 + wslot) * 2 + sub;

  float rs_i = 0.5f * (ownsum[row] + insum[row]);
  float rn_i = 1.f / (rs_i + 1e-8f);
  float di_i = rsqrtf(fmaxf(1.f + rs_i * rn_i, 1e-12f));
  float cc = 0.5f * di_i * rn_i;
  float acc = (di_i * di_i) * XWsrc[(size_t)row*32 + ol];
#pragma unroll
  for (int t = 0; t < K; ++t) {
    int j = eidx[row*K + t]; float v = evals[row*K + t];
    float dj = dinv_of(ownsum[j], insum[j]);
    acc = fmaf(cc * v * dj, XWsrc[(size_t)j*32 + ol], acc);
  }
  int ne = min(indeg[row], CIN);
  for (int e = 0; e < ne; ++e) {
    int j = incol[(size_t)row*CIN + e]; float v = inval[(size_t)row*CIN + e];
    float dj = dinv_of(ownsum[j], insum[j]);
    acc = fmaf(cc * v * dj, XWsrc[(size_t)j*32 + ol], acc);
  }
  float u0 = acc + gb[ol];
  float s = u0;
#pragma unroll
  for (int m = 1; m < 32; m <<= 1) s += __shfl_xor(s, m);
  float mean = s * (1.f/32.f);
  float d0 = u0 - mean;
  float vs = d0*d0;
#pragma unroll
  for (int m = 1; m < 32; m <<= 1) vs += __shfl_xor(vs, m);
  float rstd = rsqrtf(vs * (1.f/32.f) + 1e-5f);
  float t0 = fmaxf(d0*rstd*lg[ol] + lb[ol], 0.f);

  // MLP residual (per-wave LDS; same-wave lockstep -> no barrier)
  float hp[DIN];
#pragma unroll
  for (int d = 0; d < DIN; ++d) hp[d] = hprev[(size_t)row*DIN + d];
  float a = b0[ol];
#pragma unroll
  for (int d = 0; d < DIN; ++d) a = fmaf(hp[d], w0[d*32 + ol], a);
  hid[wslot][sub][ol] = fmaxf(a, 0.f);
  float o = b1[ol];
#pragma unroll
  for (int h = 0; h < 32; ++h) o = fmaf(hid[wslot][sub][h], w1[h*32 + ol], o);
  float hv = t0 + o;
  outp[(size_t)row*32 + ol] = hv;

  // epilogue: XWnext = h @ Wnext (h row shared via LDS)
  hid[wslot][sub][ol] = hv;
#pragma unroll
  for (int k2 = 0; k2 < NEXTD/32; ++k2) {
    int oc = ol + 32*k2;
    float acc2 = 0.f;
#pragma unroll
    for (int d = 0; d < 32; ++d)
      acc2 = fmaf(hid[wslot][sub][d], Wnext[d*NEXTD + oc], acc2);
    XWnext[(size_t)row*NEXTD + oc] = acc2;
  }
}

// ---------------- final layer (DOUT=128): R16 gather + LDS-staged w1 MLP ----
__global__ __launch_bounds__(256) void k_gpost128(
    const float* __restrict__ XW,
    const int* __restrict__ eidx, const float* __restrict__ evals,
    const unsigned short* __restrict__ incol, const float* __restrict__ inval,
    const int* __restrict__ indeg,
    const float* __restrict__ ownsum, const float* __restrict__ insum,
    const float* __restrict__ b, const float* __restrict__ g, const float* __restrict__ bt,
    const float* __restrict__ hprev,
    const float* __restrict__ w0, const float* __restrict__ b0,
    const float* __restrict__ w1, const float* __restrict__ b1,
    float* __restrict__ out, int N) {
  __shared__ float hid_s[4][128];
  __shared__ float w1s[2048];          // 16 h-rows x 128 cols chunk (8 KB)
  int wslot = threadIdx.x >> 6;
  int row   = (blockIdx.x * blockDim.x + threadIdx.x) >> 6;
  int lane  = threadIdx.x & 63;
  int o0 = lane, o1 = lane + 64;

  float rs_i = 0.5f * (ownsum[row] + insum[row]);
  float rn_i = 1.f / (rs_i + 1e-8f);
  float di_i = rsqrtf(fmaxf(1.f + rs_i * rn_i, 1e-12f));
  float cc = 0.5f * di_i * rn_i;
  float sc = di_i * di_i;
  float acc0 = sc * XW[(size_t)row*128 + o0];
  float acc1 = sc * XW[(size_t)row*128 + o1];
#pragma unroll
  for (int t = 0; t < K; ++t) {
    int j = eidx[row*K + t]; float v = evals[row*K + t];
    float dj = dinv_of(ownsum[j], insum[j]);
    float cf = cc * v * dj;
    acc0 = fmaf(cf, XW[(size_t)j*128 + o0], acc0);
    acc1 = fmaf(cf, XW[(size_t)j*128 + o1], acc1);
  }
  int ne = min(indeg[row], CIN);
  for (int e = 0; e < ne; ++e) {
    int j = incol[(size_t)row*CIN + e]; float v = inval[(size_t)row*CIN + e];
    float dj = dinv_of(ownsum[j], insum[j]);
    float cf = cc * v * dj;
    acc0 = fmaf(cf, XW[(size_t)j*128 + o0], acc0);
    acc1 = fmaf(cf, XW[(size_t)j*128 + o1], acc1);
  }
  float u0 = acc0 + b[o0];
  float u1 = acc1 + b[o1];

  float s = u0 + u1;
#pragma unroll
  for (int m = 1; m < 64; m <<= 1) s += __shfl_xor(s, m);
  float mean = s * (1.f/128.f);
  float d0 = u0 - mean, d1 = u1 - mean;
  float vs = d0*d0 + d1*d1;
#pragma unroll
  for (int m = 1; m < 64; m <<= 1) vs += __shfl_xor(vs, m);
  float rstd = rsqrtf(vs * (1.f/128.f) + 1e-5f);
  float t0 = fmaxf(d0*rstd*g[o0] + bt[o0], 0.f);
  float t1 = fmaxf(d1*rstd*g[o1] + bt[o1], 0.f);

  float hp[32];
#pragma unroll
  for (int d = 0; d < 32; ++d) hp[d] = hprev[(size_t)row*32 + d];
  {
    float a = b0[o0];
#pragma unroll
    for (int d = 0; d < 32; ++d) a = fmaf(hp[d], w0[d*128 + o0], a);
    hid_s[wslot][o0] = fmaxf(a, 0.f);
    float a1 = b0[o1];
#pragma unroll
    for (int d = 0; d < 32; ++d) a1 = fmaf(hp[d], w0[d*128 + o1], a1);
    hid_s[wslot][o1] = fmaxf(a1, 0.f);
  }

  // out = hid @ w1 with w1 staged through LDS in 8 chunks of 16 rows.
  // All 4 waves share each chunk -> w1 global traffic /4, loads become LDS reads.
  float r0=0.f, r1=0.f, r2=0.f, r3=0.f, q0=0.f, q1=0.f, q2=0.f, q3=0.f;
  for (int c = 0; c < 8; ++c) {
    __syncthreads();
    {
      const float4* src = (const float4*)(w1 + c*2048);
      float4* dst = (float4*)w1s;
      dst[threadIdx.x]       = src[threadIdx.x];
      dst[threadIdx.x + 256] = src[threadIdx.x + 256];
    }
    __syncthreads();
    int hb = c*16;
#pragma unroll
    for (int hh = 0; hh < 16; hh += 4) {
      float h0 = hid_s[wslot][hb+hh+0], h1 = hid_s[wslot][hb+hh+1],
            h2 = hid_s[wslot][hb+hh+2], h3 = hid_s[wslot][hb+hh+3];
      r0 = fmaf(h0, w1s[(hh+0)*128 + o0], r0); q0 = fmaf(h0, w1s[(hh+0)*128 + o1], q0);
      r1 = fmaf(h1, w1s[(hh+1)*128 + o0], r1); q1 = fmaf(h1, w1s[(hh+1)*128 + o1], q1);
      r2 = fmaf(h2, w1s[(hh+2)*128 + o0], r2); q2 = fmaf(h2, w1s[(hh+2)*128 + o1], q2);
      r3 = fmaf(h3, w1s[(hh+3)*128 + o0], r3); q3 = fmaf(h3, w1s[(hh+3)*128 + o1], q3);
    }
  }
  out[(size_t)row*128 + o0] = t0 + b1[o0] + ((r0 + r1) + (r2 + r3));
  out[(size_t)row*128 + o1] = t1 + b1[o1] + ((q0 + q1) + (q2 + q3));
}

extern "C" void kernel_launch(void* const* d_in, const int* in_sizes, int n_in,
                              void* d_out, int out_size, void* d_ws, size_t ws_size,
                              hipStream_t stream) {
  const float* x    = (const float*)d_in[0];
  const float* Wp   = (const float*)d_in[1];
  const float* bp   = (const float*)d_in[2];
  const float* gw0  = (const float*)d_in[3];
  const float* gb0  = (const float*)d_in[4];
  const float* gw1  = (const float*)d_in[5];
  const float* gb1  = (const float*)d_in[6];
  const float* gw2  = (const float*)d_in[7];
  const float* gb2  = (const float*)d_in[8];
  const float* lg0  = (const float*)d_in[9];
  const float* lb0  = (const float*)d_in[10];
  const float* lg1  = (const float*)d_in[11];
  const float* lb1  = (const float*)d_in[12];
  const float* lg2  = (const float*)d_in[13];
  const float* lb2  = (const float*)d_in[14];
  const float* riw0 = (const float*)d_in[15];
  const float* rib0 = (const float*)d_in[16];
  const float* riw1 = (const float*)d_in[17];
  const float* rib1 = (const float*)d_in[18];
  const float* rhw0 = (const float*)d_in[19];
  const float* rhb0 = (const float*)d_in[20];
  const float* rhw1 = (const float*)d_in[21];
  const float* rhb1 = (const float*)d_in[22];
  const float* row0 = (const float*)d_in[23];
  const float* rob0 = (const float*)d_in[24];
  const float* row1 = (const float*)d_in[25];
  const float* rob1 = (const float*)d_in[26];
  int N = in_sizes[0] / D_IN;   // 8192
  float* out = (float*)d_out;

  char* ws = (char*)d_ws;
  size_t off = 0;
  auto alloc = [&](size_t bytes) -> void* {
    void* p = ws + off;
    off += (bytes + 255) & ~(size_t)255;
    return p;
  };
  float* hn      = (float*)alloc((size_t)N * HP * 4);
  float* evals   = (float*)alloc((size_t)N * K * 4);
  int*   eidx    = (int*)  alloc((size_t)N * K * 4);
  float* ownsum  = (float*)alloc((size_t)N * 4);
  float* insum   = (float*)alloc((size_t)N * 4);
  int*   indeg   = (int*)  alloc((size_t)N * 4);
  float* XWa     = (float*)alloc((size_t)N * 128 * 4);
  float* XWb     = (float*)alloc((size_t)N * 32 * 4);
  float* h1      = (float*)alloc((size_t)N * 32 * 4);
  float* h2      = (float*)alloc((size_t)N * 32 * 4);
  float* tau     = (float*)alloc((size_t)N * 4);
  int*   cnt     = (int*)  alloc((size_t)N * NC * 4);
  unsigned short* buf = (unsigned short*)alloc((size_t)N * NC * CAPC * 2);
  short* hnb     = (short*)alloc((size_t)N * 32 * 2);
  unsigned short* incol = (unsigned short*)alloc((size_t)N * CIN * 2);
  float* inval   = (float*)alloc((size_t)N * CIN * 4);
  (void)ws_size; (void)n_in; (void)out_size;

  const int B = 256;
  hipLaunchKernelGGL(k_proj, dim3((N + B - 1) / B), dim3(B), 0, stream,
                     x, Wp, bp, gw0, hn, hnb, XWa, insum, indeg, N);
  hipLaunchKernelGGL(k_thresh, dim3(N / 4), dim3(B), 0, stream, hn, tau, N);
  hipLaunchKernelGGL(k_scan2, dim3((N / 16) * NC), dim3(B), 0, stream, hnb, tau, cnt, buf, N);
  hipLaunchKernelGGL(k_final, dim3(N / 4), dim3(B), 0, stream,
                     hn, buf, cnt, evals, eidx, ownsum, insum, indeg, incol, inval, N);

  // layer 0: XWa(stride32) -> h1, epilogue XWb = h1 @ gw1
  hipLaunchKernelGGL((k_gpost32<20, 32>), dim3(N / 8), dim3(B), 0, stream,
                     XWa, eidx, evals, incol, inval, indeg, ownsum, insum,
                     gb0, lg0, lb0, x, riw0, rib0, riw1, rib1, gw1, XWb, h1, N);
  // layer 1: XWb(stride32) -> h2, epilogue XWa = h2 @ gw2 (stride128)
  hipLaunchKernelGGL((k_gpost32<32, 128>), dim3(N / 8), dim3(B), 0, stream,
                     XWb, eidx, evals, incol, inval, indeg, ownsum, insum,
                     gb1, lg1, lb1, h1, rhw0, rhb0, rhw1, rhb1, gw2, XWa, h2, N);
  // layer 2: XWa(stride128) -> out
  hipLaunchKernelGGL(k_gpost128, dim3(N / 4), dim3(B), 0, stream,
                     XWa, eidx, evals, incol, inval, indeg, ownsum, insum,
                     gb2, lg2, lb2, h2, row0, rob0, row1, rob1, out, N);
}